// Round 5
// baseline (2089.064 us; speedup 1.0000x reference)
//
#include <hip/hip_runtime.h>
#include <hip/hip_bf16.h>

// Bi-LSTM persistent kernel v5. B=32, T=512, D=H=512.
// 4 sync groups = dir(2) x batch-half(2); 16 WGs/group, 16 rows, 32 h-cols/WG.
// Sync: tag-in-data, per-producer granularity. Producer epilogue stores h as
// tagged u64 {lo32 tag=s+1, hi32 2xbf16} — no drain, no flag, no global barrier.
// Consumer waves each wait on only 4 producers (their K=128 slice), consuming
// chunks progressively as tags appear; poll IS the data load (2-RTT chain).
#define Bz 32
#define Tz 512
#define Dz 512
#define Hz 512
#define NG 4      // sync groups
#define GWG 16    // producers (WGs) per group
#define ROWS 16   // batch rows per group (one MFMA m-tile)
#define COLS 32   // h-cols per WG
#define NT 8      // n-tiles per WG (4 gates x 2 col-halves)

typedef __attribute__((ext_vector_type(8))) short short8;
typedef __attribute__((ext_vector_type(4))) float f32x4;

// tagged words: [group][parity][producer][row][colpair] u64 = {tag, 2xbf16}
#define TPU 4096                         // u64 per (group,parity) = 16*16*16
#define TPB (TPU * 8)                    // 32 KB
#define WS_X  (NG * 2 * TPB)             // 256 KB, then x in bf16 (16 MB)
#define WS_NEED ((size_t)WS_X + (size_t)Bz * Tz * Dz * 2)

__device__ __forceinline__ unsigned short f2bf(float f) {
    return __builtin_bit_cast(unsigned short, __float2bfloat16(f));
}
__device__ __forceinline__ float rcp_(float x) { return __builtin_amdgcn_rcpf(x); }
__device__ __forceinline__ float fsig(float x) { return rcp_(1.0f + __expf(-x)); }
__device__ __forceinline__ float ftanh(float x) {
    float t = __expf(-2.0f * fabsf(x));
    return copysignf((1.0f - t) * rcp_(1.0f + t), x);
}

// Zero tagged region (tag 0 + h=0 is the initial state); convert x fp32->bf16.
__global__ void init_kernel(const float* __restrict__ x, unsigned char* __restrict__ ws, int do_x) {
    int tid = blockIdx.x * blockDim.x + threadIdx.x;
    unsigned int* w32 = (unsigned int*)ws;
    if (tid < (WS_X / 4)) w32[tid] = 0u;
    if (do_x) {
        const int n4 = (Bz * Tz * Dz) / 4;
        if (tid < n4) {
            const float4* xin = (const float4*)x;
            float4 v = xin[tid];
            unsigned int u0 = (unsigned)f2bf(v.x) | ((unsigned)f2bf(v.y) << 16);
            unsigned int u1 = (unsigned)f2bf(v.z) | ((unsigned)f2bf(v.w) << 16);
            unsigned int* xo = (unsigned int*)(ws + WS_X);
            xo[tid * 2]     = u0;
            xo[tid * 2 + 1] = u1;
        }
    }
}

template <bool XB>
__launch_bounds__(256, 1)
__global__ void lstm_kernel(const float* __restrict__ xf,
                            const float* __restrict__ Wf, const float* __restrict__ bf,
                            const float* __restrict__ Wb, const float* __restrict__ bb,
                            float* __restrict__ out, unsigned char* __restrict__ ws) {
    const int bi   = blockIdx.x;
    const int dir  = bi & 1;
    const int grp  = (bi >> 1) & 1;
    const int wg   = bi >> 2;            // 0..15
    const int gid  = dir * 2 + grp;
    const int j0   = wg * COLS;
    const int b0   = grp * ROWS;
    const int tid  = threadIdx.x;
    const int wave = tid >> 6;
    const int lane = tid & 63;
    const int nidx = lane & 15;          // A-frag row m / B-frag col n
    const int quad = lane >> 4;

    const float* W    = dir ? Wb : Wf;
    const float* bias = dir ? bb : bf;

    unsigned long long* tp = (unsigned long long*)(ws + (size_t)gid * 2 * TPB);
    const unsigned short* xbf = (const unsigned short*)(ws + WS_X);

    __shared__ float part[4][NT][16][18];   // wave, ntile, row, col (+2 pad, 8B-aligned)

    // --- one-time: full W slice (x and h parts) as B-fragments in registers ---
    // wave covers K-chunks {4*wave .. 4*wave+3} (chunk = 32 K) for both Wx and Wh.
    short8 bx[4][NT], bh[4][NT];
    const int w4 = wave * 4;
    #pragma unroll
    for (int i = 0; i < 4; ++i) {
        const int k0 = 32 * (w4 + i) + quad * 8;
        #pragma unroll
        for (int nt = 0; nt < NT; ++nt) {
            const int col = (nt >> 1) * 512 + j0 + (nt & 1) * 16 + nidx;
            short8 vx, vh;
            #pragma unroll
            for (int jj = 0; jj < 8; ++jj) {
                vx[jj] = (short)f2bf(W[(k0 + jj) * (4 * Hz) + col]);
                vh[jj] = (short)f2bf(W[(512 + k0 + jj) * (4 * Hz) + col]);
            }
            bx[i][nt] = vx;
            bh[i][nt] = vh;
        }
    }

    // --- per-thread epilogue state: 1 row x 2 cols each ---
    const int erow = tid >> 4;           // 0..15
    const int e    = tid & 15;
    const int c0   = 2 * e;              // cols c0, c0+1 (same 16-col half)
    const int ci   = c0 & 15;
    const int nt0  = c0 >> 4;
    float bia[4][2];
    #pragma unroll
    for (int g = 0; g < 4; ++g) {
        bia[g][0] = bias[g * 512 + j0 + c0];
        bia[g][1] = bias[g * 512 + j0 + c0 + 1];
    }
    float cr0 = 0.f, cr1 = 0.f;
    float* outp = out + ((size_t)(b0 + erow) * Tz) * (2 * Hz) + dir * Hz + j0 + c0;

    f32x4 acc[NT];
    auto xpart = [&](int t) {
        #pragma unroll
        for (int nt = 0; nt < NT; ++nt) acc[nt] = (f32x4){0.f, 0.f, 0.f, 0.f};
        #pragma unroll
        for (int i = 0; i < 4; ++i) {
            const int k = 32 * (w4 + i) + quad * 8;
            short8 ax;
            if (XB) {
                ax = *(const short8*)(xbf + ((size_t)(b0 + nidx) * Tz + t) * Dz + k);
            } else {
                const float* q = xf + ((size_t)(b0 + nidx) * Tz + t) * Dz + k;
                #pragma unroll
                for (int jj = 0; jj < 8; ++jj) ax[jj] = (short)f2bf(q[jj]);
            }
            #pragma unroll
            for (int nt = 0; nt < NT; ++nt)
                acc[nt] = __builtin_amdgcn_mfma_f32_16x16x32_bf16(ax, bx[i][nt], acc[nt], 0, 0, 0);
        }
    };

    xpart(dir ? (Tz - 1) : 0);   // step 0's x-part

    for (int s = 0; s < Tz; ++s) {
        // --- progressive consume: poll IS the load; MFMA each chunk on arrival ---
        {
            const unsigned long long* tpr = tp + (size_t)(s & 1) * TPU;
            const unsigned tg = (unsigned)s;
            unsigned rm = 0;
            while (rm != 0xFu) {
                bool prog = false;
                #pragma unroll
                for (int i = 0; i < 4; ++i) if (!((rm >> i) & 1u)) {
                    const unsigned long long* bp = tpr + (((w4 + i) * 16 + nidx) * 16 + quad * 4);
                    unsigned long long v0 = __hip_atomic_load(bp + 0, __ATOMIC_RELAXED, __HIP_MEMORY_SCOPE_AGENT);
                    unsigned long long v1 = __hip_atomic_load(bp + 1, __ATOMIC_RELAXED, __HIP_MEMORY_SCOPE_AGENT);
                    unsigned long long v2 = __hip_atomic_load(bp + 2, __ATOMIC_RELAXED, __HIP_MEMORY_SCOPE_AGENT);
                    unsigned long long v3 = __hip_atomic_load(bp + 3, __ATOMIC_RELAXED, __HIP_MEMORY_SCOPE_AGENT);
                    int ok = ((unsigned)v0 == tg) & ((unsigned)v1 == tg) &
                             ((unsigned)v2 == tg) & ((unsigned)v3 == tg);
                    if (__ballot(ok) == ~0ull) {
                        unsigned h0 = (unsigned)(v0 >> 32), h1 = (unsigned)(v1 >> 32);
                        unsigned h2 = (unsigned)(v2 >> 32), h3 = (unsigned)(v3 >> 32);
                        short8 a;
                        a[0] = (short)h0; a[1] = (short)(h0 >> 16);
                        a[2] = (short)h1; a[3] = (short)(h1 >> 16);
                        a[4] = (short)h2; a[5] = (short)(h2 >> 16);
                        a[6] = (short)h3; a[7] = (short)(h3 >> 16);
                        #pragma unroll
                        for (int nt = 0; nt < NT; ++nt)
                            acc[nt] = __builtin_amdgcn_mfma_f32_16x16x32_bf16(a, bh[i][nt], acc[nt], 0, 0, 0);
                        rm |= 1u << i;
                        prog = true;
                    }
                }
                if (!prog && rm != 0xFu) __builtin_amdgcn_s_sleep(1);
            }
        }

        // --- cross-wave partial reduce via LDS ---
        {
            const int r0 = quad * 4;
            #pragma unroll
            for (int nt = 0; nt < NT; ++nt)
                #pragma unroll
                for (int r = 0; r < 4; ++r)
                    part[wave][nt][r0 + r][nidx] = acc[nt][r];
        }
        __syncthreads();

        // --- epilogue: gates, state update, tagged publish, out store ---
        const int t = dir ? (Tz - 1 - s) : s;
        {
            float z[4][2];
            #pragma unroll
            for (int g = 0; g < 4; ++g) {
                const int nt = g * 2 + nt0;
                float sx = bia[g][0], sy = bia[g][1];
                #pragma unroll
                for (int w = 0; w < 4; ++w) {
                    const float2 p = *(const float2*)&part[w][nt][erow][ci];
                    sx += p.x; sy += p.y;
                }
                z[g][0] = sx; z[g][1] = sy;
            }
            float cA = fsig(z[1][0]) * cr0 + fsig(z[0][0]) * ftanh(z[3][0]); cr0 = cA;
            float hA = fsig(z[2][0]) * ftanh(cA);
            float cB = fsig(z[1][1]) * cr1 + fsig(z[0][1]) * ftanh(z[3][1]); cr1 = cB;
            float hB = fsig(z[2][1]) * ftanh(cB);

            unsigned pk = (unsigned)f2bf(hA) | ((unsigned)f2bf(hB) << 16);
            unsigned long long val = ((unsigned long long)pk << 32) | (unsigned)(s + 1);
            unsigned long long* tpw = tp + (size_t)((s + 1) & 1) * TPU + ((wg * 16 + erow) * 16 + e);
            __hip_atomic_store(tpw, val, __ATOMIC_RELAXED, __HIP_MEMORY_SCOPE_AGENT);

            float2 ov; ov.x = hA; ov.y = hB;
            *(float2*)(outp + (size_t)t * (2 * Hz)) = ov;
        }
        __syncthreads();   // LDS reuse guard

        if (s + 1 < Tz) xpart(dir ? (Tz - 2 - s) : (s + 1));   // next step's x-part in the gap
    }
}

extern "C" void kernel_launch(void* const* d_in, const int* in_sizes, int n_in,
                              void* d_out, int out_size, void* d_ws, size_t ws_size,
                              hipStream_t stream) {
    const float* x  = (const float*)d_in[0];
    const float* Wf = (const float*)d_in[1];
    const float* bf = (const float*)d_in[2];
    const float* Wb = (const float*)d_in[3];
    const float* bb = (const float*)d_in[4];
    float* out = (float*)d_out;
    unsigned char* ws = (unsigned char*)d_ws;
    const bool xb = (ws_size >= WS_NEED);

    init_kernel<<<8192, 256, 0, stream>>>(x, ws, xb ? 1 : 0);
    if (xb)
        lstm_kernel<true><<<NG * GWG, 256, 0, stream>>>(x, Wf, bf, Wb, bb, out, ws);
    else
        lstm_kernel<false><<<NG * GWG, 256, 0, stream>>>(x, Wf, bf, Wb, bb, out, ws);
}